// Round 13
// baseline (89.528 us; speedup 1.0000x reference)
//
#include <hip/hip_runtime.h>
#include <hip/hip_bf16.h>
#include <math.h>

#define BATCH 4096
#define TWO_B 8192
#define DIM 128
#define NB 16384
#define COS_EPS 1e-8f
#define LOSS_EPS 1e-6f
// 1/TEMP ; log2(e)/TEMP ; sqrt(log2(e)/TEMP) ; ln 2
#define INV_TEMP 14.285714285714286f
#define EXP2_SCALE 20.60992915555662f
#define SQRT_EXP2_SCALE 4.5398166f
#define LN2 0.6931471805599453f

#define N_NEAR 32768
#define GRAM_BLOCKS 520             // 4 pairs/block x 520 = 2080 = #{(I,J): I<=J<64}
#define STR 144                     // padded half-K row stride (128 B data + 16 B pad)
#define BUFSZ (256 * STR)           // A(128 rows) + B(128 rows) per buffer

typedef __attribute__((ext_vector_type(8))) short bf16x8;
typedef __attribute__((ext_vector_type(4))) float f32x4;

__device__ __forceinline__ float fast_exp2(float x) {
#if __has_builtin(__builtin_amdgcn_exp2f)
  return __builtin_amdgcn_exp2f(x);
#else
  float r;
  asm("v_exp_f32 %0, %1" : "=v"(r) : "v"(x));
  return r;
#endif
}

__device__ __forceinline__ float2 bf2_to_f2(unsigned int w) {
  float2 r;
  r.x = __uint_as_float(w << 16);
  r.y = __uint_as_float(w & 0xffff0000u);
  return r;
}

// ---------------- K1: normalize za rows -> bf16 za_n (pre-scaled); inv_zn; zero augacc/out ----------------
__global__ __launch_bounds__(256) void k_normalize(
    const float* __restrict__ z1, const float* __restrict__ z2,
    const float* __restrict__ zn,
    __hip_bfloat16* __restrict__ za_n, float* __restrict__ inv_zn,
    float* __restrict__ augacc, float* __restrict__ out) {
  if (blockIdx.x == 0 && threadIdx.x == 0) { augacc[0] = 0.0f; out[0] = 0.0f; }
  int wave = (blockIdx.x * blockDim.x + threadIdx.x) >> 6;
  int lane = threadIdx.x & 63;
  if (wave >= TWO_B + NB) return;
  const float* src;
  if (wave < BATCH) src = z1 + (size_t)wave * DIM;
  else if (wave < TWO_B) src = z2 + (size_t)(wave - BATCH) * DIM;
  else src = zn + (size_t)(wave - TWO_B) * DIM;
  float2 v = ((const float2*)src)[lane];
  float ss = v.x * v.x + v.y * v.y;
#pragma unroll
  for (int m = 1; m < 64; m <<= 1) ss += __shfl_xor(ss, m, 64);
  float inv = 1.0f / fmaxf(sqrtf(ss), COS_EPS);
  if (wave < TWO_B) {
    float s = inv * SQRT_EXP2_SCALE;   // fold exp2 scale into the data
    __hip_bfloat162 o;
    o.x = __float2bfloat16(v.x * s);
    o.y = __float2bfloat16(v.y * s);
    ((__hip_bfloat162*)(za_n + (size_t)wave * DIM))[lane] = o;
  } else {
    if (lane == 0) inv_zn[wave - TWO_B] = inv;
  }
}

// ---------------- K2: pipelined symmetric Gram: 4 pairs/block, double-buffered halves ----------------
__global__ __launch_bounds__(256) void k_gram(
    const __hip_bfloat16* __restrict__ za_n, const float* __restrict__ zn,
    const float* __restrict__ inv_zn,
    float* __restrict__ part_row, float* __restrict__ part_col,
    float* __restrict__ pos_partial, float* __restrict__ augacc) {
  __shared__ char lds[2 * BUFSZ];          // 73.7 KB double buffer
  __shared__ float sc_row[2][2][128];      // [parity][wc][local row]
  __shared__ float sc_col[2][2][128];      // [parity][wr][local col]
  const int t = threadIdx.x;
  const int w = t >> 6, lane = t & 63;
  const int wr = w & 1, wc = w >> 1;
  const int lhi = lane >> 4, llo = lane & 15;
  const char* za8 = (const char*)za_n;     // row stride 256 B

  // closed-form pair map: pid -> (I,J); boundary discriminant is a perfect square
  int I[4], J[4];
#pragma unroll
  for (int q = 0; q < 4; ++q) {
    int pid = blockIdx.x * 4 + q;
    float sq = sqrtf(16641.0f - 8.0f * (float)pid);
    int Iv = (int)floorf((129.0f - sq) * 0.5f + 1e-4f);
    I[q] = Iv;
    J[q] = Iv + pid - (129 * Iv - Iv * Iv) / 2;
  }

  // per-lane addresses (everything else is compile-time immediate)
  const int st_row = t >> 3, st_ch = (t & 7) * 16;   // staging: 32 rows x 8 chunks/iter
  const int vW = st_row * STR + st_ch;               // ds_write base (A); B adds 128*STR
  const int vA = (wr * 64 + llo) * STR + lhi * 16;   // frag base A
  const int vB = (128 + wc * 64 + llo) * STR + lhi * 16;

  uint4 rA[4], rB[4];
  f32x4 acc[4][4];

#define ISSUE(q, h)                                                             \
  { const size_t ib = (size_t)(I[q] * 128) * 256 + (h) * 128 + st_ch;           \
    const size_t jb = (size_t)(J[q] * 128) * 256 + (h) * 128 + st_ch;           \
    _Pragma("unroll")                                                           \
    for (int it = 0; it < 4; ++it) {                                            \
      rA[it] = *(const uint4*)(za8 + ib + (size_t)(it * 32 + st_row) * 256);    \
      rB[it] = *(const uint4*)(za8 + jb + (size_t)(it * 32 + st_row) * 256);    \
    } }

#define WRITEB(b)                                                               \
  { _Pragma("unroll")                                                           \
    for (int it = 0; it < 4; ++it) {                                            \
      *(uint4*)(lds + (b) * BUFSZ + vW + it * 32 * STR) = rA[it];               \
      *(uint4*)(lds + (b) * BUFSZ + 128 * STR + vW + it * 32 * STR) = rB[it];   \
    } }

#define ZEROACC                                                                 \
  { _Pragma("unroll") for (int rt = 0; rt < 4; ++rt)                            \
    _Pragma("unroll") for (int ct = 0; ct < 4; ++ct) acc[rt][ct] = (f32x4)0.0f; }

#define COMPUTE(b)                                                              \
  { _Pragma("unroll")                                                           \
    for (int ks = 0; ks < 2; ++ks) {                                            \
      bf16x8 af[4], bfr[4];                                                     \
      _Pragma("unroll") for (int rt = 0; rt < 4; ++rt)                          \
        af[rt] = *(const bf16x8*)(lds + (b) * BUFSZ + vA + rt * 16 * STR + ks * 64); \
      _Pragma("unroll") for (int ct = 0; ct < 4; ++ct)                          \
        bfr[ct] = *(const bf16x8*)(lds + (b) * BUFSZ + vB + ct * 16 * STR + ks * 64); \
      _Pragma("unroll") for (int rt = 0; rt < 4; ++rt)                          \
        _Pragma("unroll") for (int ct = 0; ct < 4; ++ct)                        \
          acc[rt][ct] = __builtin_amdgcn_mfma_f32_16x16x32_bf16(                \
              af[rt], bfr[ct], acc[rt][ct], 0, 0, 0);                           \
    } }

#define EPILOGUE(q, par)                                                        \
  { if (J[q] - I[q] == 32) {                                                    \
      float ap = 0.0f;                                                          \
      _Pragma("unroll") for (int rt = 0; rt < 4; ++rt) {                        \
        const int lrb = wr * 64 + rt * 16 + lhi * 4;                            \
        _Pragma("unroll") for (int ct = 0; ct < 4; ++ct) {                      \
          const int lc = wc * 64 + ct * 16 + llo;                               \
          _Pragma("unroll") for (int g = 0; g < 4; ++g)                         \
            if (lc == lrb + g) ap += acc[rt][ct][g];                            \
        }                                                                       \
      }                                                                         \
      _Pragma("unroll") for (int m = 1; m < 64; m <<= 1) ap += __shfl_xor(ap, m, 64); \
      if (lane == 0) atomicAdd(augacc, ap);                                     \
    }                                                                           \
    float cp[4] = {0.0f, 0.0f, 0.0f, 0.0f};                                     \
    _Pragma("unroll") for (int rt = 0; rt < 4; ++rt) {                          \
      const int lrowb = wr * 64 + rt * 16 + lhi * 4;                            \
      float rp[4] = {0.0f, 0.0f, 0.0f, 0.0f};                                   \
      if (I[q] == J[q]) {                                                       \
        _Pragma("unroll") for (int ct = 0; ct < 4; ++ct) {                      \
          const int lcol = wc * 64 + ct * 16 + llo;                             \
          _Pragma("unroll") for (int g = 0; g < 4; ++g) {                       \
            float e = fast_exp2(acc[rt][ct][g]);                                \
            e = (lcol > lrowb + g) ? e : 0.0f;                                  \
            rp[g] += e; cp[ct] += e;                                            \
          }                                                                     \
        }                                                                       \
      } else {                                                                  \
        _Pragma("unroll") for (int ct = 0; ct < 4; ++ct)                        \
          _Pragma("unroll") for (int g = 0; g < 4; ++g) {                       \
            float e = fast_exp2(acc[rt][ct][g]);                                \
            rp[g] += e; cp[ct] += e;                                            \
          }                                                                     \
      }                                                                         \
      _Pragma("unroll") for (int g = 0; g < 4; ++g) {                           \
        float s = rp[g];                                                        \
        s += __shfl_xor(s, 1, 64); s += __shfl_xor(s, 2, 64);                   \
        s += __shfl_xor(s, 4, 64); s += __shfl_xor(s, 8, 64);                   \
        if (llo == 0) sc_row[par][wc][lrowb + g] = s;                           \
      }                                                                         \
    }                                                                           \
    _Pragma("unroll") for (int ct = 0; ct < 4; ++ct) {                          \
      float s = cp[ct];                                                         \
      s += __shfl_xor(s, 16, 64); s += __shfl_xor(s, 32, 64);                   \
      if (lhi == 0) sc_col[par][wr][wc * 64 + ct * 16 + llo] = s;               \
    } }

#define STOREP(q, par)                                                          \
  { if (t < 128)                                                                \
      part_row[(size_t)(I[q] * 64 + J[q]) * 128 + t] =                          \
          sc_row[par][0][t] + sc_row[par][1][t];                                \
    else                                                                        \
      part_col[(size_t)(J[q] * 64 + I[q]) * 128 + (t - 128)] =                  \
          sc_col[par][0][t - 128] + sc_col[par][1][t - 128]; }

  // ---------- pipeline: 8 half-items, 1 barrier each ----------
  ISSUE(0, 0); WRITEB(0);
  ISSUE(0, 1);
  __syncthreads();

  ZEROACC; COMPUTE(0);                 // n=0: pair0 h0
  WRITEB(1); ISSUE(1, 0);
  __syncthreads();

  COMPUTE(1);                          // n=1: pair0 h1
  EPILOGUE(0, 0);
  WRITEB(0); ISSUE(1, 1);
  __syncthreads();
  STOREP(0, 0);

  ZEROACC; COMPUTE(0);                 // n=2: pair1 h0
  WRITEB(1); ISSUE(2, 0);
  __syncthreads();

  COMPUTE(1);                          // n=3: pair1 h1
  EPILOGUE(1, 1);
  WRITEB(0); ISSUE(2, 1);
  __syncthreads();
  STOREP(1, 1);

  ZEROACC; COMPUTE(0);                 // n=4: pair2 h0
  WRITEB(1); ISSUE(3, 0);
  __syncthreads();

  COMPUTE(1);                          // n=5: pair2 h1
  EPILOGUE(2, 0);
  WRITEB(0); ISSUE(3, 1);
  __syncthreads();
  STOREP(2, 0);

  ZEROACC; COMPUTE(0);                 // n=6: pair3 h0
  WRITEB(1);
  __syncthreads();

  COMPUTE(1);                          // n=7: pair3 h1
  EPILOGUE(3, 1);
  __syncthreads();
  STOREP(3, 1);

  // ---- fused nearby positives: blocks 0..511, 64 dots each (16/wave, 4-lane groups) ----
  if (blockIdx.x < 512) {
    const int sub = lane & 3;
    const int k = blockIdx.x * 64 + w * 16 + (lane >> 2);
    int zr, zc;
    if (k < BATCH)                { zr = BATCH + k; zc = k; }
    else if (k < BATCH + TWO_B)   { int q = k - BATCH;             zr = q; zc = q; }
    else if (k < BATCH + 2*TWO_B) { int q = k - BATCH - TWO_B;     zr = q; zc = q + BATCH; }
    else if (k < BATCH + 3*TWO_B) { int q = k - BATCH - 2*TWO_B;   zr = q; zc = q + 2*BATCH; }
    else                          { int q = k - BATCH - 3*TWO_B;   zr = q; zc = q + 3*BATCH; }
    const uint4* aro = (const uint4*)(za_n + (size_t)zr * DIM);    // 16 chunks of 8 bf16
    const float4* bro = (const float4*)(zn + (size_t)zc * DIM);
    float d = 0.0f;
#pragma unroll
    for (int c = 0; c < 4; ++c) {
      uint4 aw = aro[sub + c * 4];
      float4 b0 = bro[(sub + c * 4) * 2];
      float4 b1 = bro[(sub + c * 4) * 2 + 1];
      float2 q2;
      q2 = bf2_to_f2(aw.x); d += q2.x * b0.x + q2.y * b0.y;
      q2 = bf2_to_f2(aw.y); d += q2.x * b0.z + q2.y * b0.w;
      q2 = bf2_to_f2(aw.z); d += q2.x * b1.x + q2.y * b1.y;
      q2 = bf2_to_f2(aw.w); d += q2.x * b1.z + q2.y * b1.w;
    }
    d += __shfl_xor(d, 1, 64);
    d += __shfl_xor(d, 2, 64);
    if (sub == 0) {
      float ds = d * inv_zn[zc] * SQRT_EXP2_SCALE;       // = sim * EXP2_SCALE
      pos_partial[k] = fminf(ds, EXP2_SCALE) * LN2;      // = min(sim,1) * INV_TEMP
    }
  }
}

// ---------------- K3: wave-per-row-octet gather + fused final (atomicAdd out) ----------------
__global__ __launch_bounds__(256) void k_reduce(
    const float* __restrict__ part_row, const float* __restrict__ part_col,
    const float* __restrict__ pos_partial, const float* __restrict__ augacc,
    float* __restrict__ out) {
  const int w = threadIdx.x >> 6, lane = threadIdx.x & 63;
  float s = 0.0f;
#pragma unroll
  for (int i = 0; i < 8; ++i) {
    const int r = blockIdx.x * 32 + w * 8 + i;
    const int I = r >> 7, rr = r & 127;
    const size_t base = (size_t)(I * 64 + lane) * 128 + rr;
    float v = 0.0f;
    if (lane >= I) v += part_row[base];
    if (lane <= I) v += part_col[base];
#pragma unroll
    for (int m = 1; m < 64; m <<= 1) v += __shfl_xor(v, m, 64);
    if (lane == 0) {
      float tl = 8.0f * logf(v + LOSS_EPS);
      tl -= pos_partial[r];
      tl -= pos_partial[r + TWO_B];
      tl -= pos_partial[r + 2 * TWO_B];
      tl -= pos_partial[r + 3 * TWO_B];
      s += tl;
    }
  }
  __shared__ float red[4];
  if (lane == 0) red[w] = s;
  __syncthreads();
  if (threadIdx.x == 0) {
    float bs = red[0] + red[1] + red[2] + red[3];
    if (blockIdx.x == 0) bs -= 8.0f * LN2 * augacc[0];  // aug positives from gram
    atomicAdd(out, bs * (1.0f / 65536.0f));
  }
}

extern "C" void kernel_launch(void* const* d_in, const int* in_sizes, int n_in,
                              void* d_out, int out_size, void* d_ws, size_t ws_size,
                              hipStream_t stream) {
  const float* z1 = (const float*)d_in[0];
  const float* z2 = (const float*)d_in[1];
  const float* zn = (const float*)d_in[2];
  float* out = (float*)d_out;

  char* ws = (char*)d_ws;
  __hip_bfloat16* za_n = (__hip_bfloat16*)ws;                  // 2 MB
  float* inv_zn      = (float*)(ws + 2097152);                 // 64 KB
  float* pos_partial = (float*)(ws + 2097152 + 65536);         // 128 KB
  float* augacc      = (float*)(ws + 2097152 + 65536 + 131072);          // 4 KB slot
  float* part_row    = (float*)(ws + 2097152 + 65536 + 131072 + 4096);   // 2 MB
  float* part_col    = (float*)(ws + 2097152 + 65536 + 131072 + 4096 + 2097152); // 2 MB

  // K1: normalize + zero augacc/out
  k_normalize<<<(TWO_B + NB) / 4, 256, 0, stream>>>(z1, z2, zn, za_n, inv_zn, augacc, out);
  // K2: pipelined symmetric gram + fused nearby positives
  k_gram<<<GRAM_BLOCKS, 256, 0, stream>>>(za_n, zn, inv_zn, part_row, part_col,
                                          pos_partial, augacc);
  // K3: gather/log/subtract + fused final scalar
  k_reduce<<<256, 256, 0, stream>>>(part_row, part_col, pos_partial, augacc, out);
}

// Round 14
// 68.162 us; speedup vs baseline: 1.3135x; 1.3135x over previous
//
#include <hip/hip_runtime.h>
#include <hip/hip_bf16.h>
#include <math.h>

#define BATCH 4096
#define TWO_B 8192
#define DIM 128
#define NB 16384
#define COS_EPS 1e-8f
#define LOSS_EPS 1e-6f
// 1/TEMP ; log2(e)/TEMP ; sqrt(log2(e)/TEMP) ; ln 2
#define INV_TEMP 14.285714285714286f
#define EXP2_SCALE 20.60992915555662f
#define SQRT_EXP2_SCALE 4.5398166f
#define LN2 0.6931471805599453f

#define N_NEAR 32768
#define GRAM_BLOCKS 544             // #{(I,g): I<64, g in [I>>2, 16)} ; 8x68 exact
#define STR 144                     // half-K row: 128 B data + 16 B pad (R11-proven)
#define AHALF (128 * STR)           // 18432 B per A half

typedef __attribute__((ext_vector_type(8))) short bf16x8;
typedef __attribute__((ext_vector_type(4))) float f32x4;

__device__ __forceinline__ float fast_exp2(float x) {
#if __has_builtin(__builtin_amdgcn_exp2f)
  return __builtin_amdgcn_exp2f(x);
#else
  float r;
  asm("v_exp_f32 %0, %1" : "=v"(r) : "v"(x));
  return r;
#endif
}

__device__ __forceinline__ float2 bf2_to_f2(unsigned int w) {
  float2 r;
  r.x = __uint_as_float(w << 16);
  r.y = __uint_as_float(w & 0xffff0000u);
  return r;
}

// ---------------- K1: normalize za rows -> bf16 za_n (pre-scaled); inv_zn; zero augacc/out ----------------
__global__ __launch_bounds__(256) void k_normalize(
    const float* __restrict__ z1, const float* __restrict__ z2,
    const float* __restrict__ zn,
    __hip_bfloat16* __restrict__ za_n, float* __restrict__ inv_zn,
    float* __restrict__ augacc, float* __restrict__ out) {
  if (blockIdx.x == 0 && threadIdx.x == 0) { augacc[0] = 0.0f; out[0] = 0.0f; }
  int wave = (blockIdx.x * blockDim.x + threadIdx.x) >> 6;
  int lane = threadIdx.x & 63;
  if (wave >= TWO_B + NB) return;
  const float* src;
  if (wave < BATCH) src = z1 + (size_t)wave * DIM;
  else if (wave < TWO_B) src = z2 + (size_t)(wave - BATCH) * DIM;
  else src = zn + (size_t)(wave - TWO_B) * DIM;
  float2 v = ((const float2*)src)[lane];
  float ss = v.x * v.x + v.y * v.y;
#pragma unroll
  for (int m = 1; m < 64; m <<= 1) ss += __shfl_xor(ss, m, 64);
  float inv = 1.0f / fmaxf(sqrtf(ss), COS_EPS);
  if (wave < TWO_B) {
    float s = inv * SQRT_EXP2_SCALE;   // fold exp2 scale into the data
    __hip_bfloat162 o;
    o.x = __float2bfloat16(v.x * s);
    o.y = __float2bfloat16(v.y * s);
    ((__hip_bfloat162*)(za_n + (size_t)wave * DIM))[lane] = o;
  } else {
    if (lane == 0) inv_zn[wave - TWO_B] = inv;
  }
}

// ---------------- K2: symmetric Gram with A-tile reuse: block = (I row-tile, 4 J-chunks) ----------------
// 544 blocks (XCD-swizzled); 4 waves of 64x64; A halves persistent in LDS, B half restaged.
// LDS 57.3 KB -> 2 blocks/CU; VGPR kept at R11 level (no reg pipelining).
__global__ __launch_bounds__(256) void k_gram(
    const __hip_bfloat16* __restrict__ za_n, const float* __restrict__ zn,
    const float* __restrict__ inv_zn,
    float* __restrict__ part_row, float* __restrict__ part_col,
    float* __restrict__ pos_partial, float* __restrict__ augacc) {
  __shared__ char ldsA[2 * AHALF];        // A K-halves, persistent across chunks
  __shared__ char ldsB[AHALF];            // B K-half, restaged per (chunk, half)
  __shared__ float sc_row[2][128];        // [wc][local row]
  __shared__ float sc_col[2][128];        // [wr][local col]
  const int t = threadIdx.x;
  const int w = t >> 6, lane = t & 63;
  const int wr = w & 1, wc = w >> 1;
  const int lhi = lane >> 4, llo = lane & 15;
  const char* za8 = (const char*)za_n;    // row stride 256 B

  // XCD swizzle: consecutive logical ids (same A-tile) land on one XCD's L2
  const int lid = (blockIdx.x & 7) * 68 + (blockIdx.x >> 3);
  // lid -> (I, g): tier k = I>>2 has 4 rows x (16-k) groups
  int k = 0, cum = 0;
  while (lid >= cum + 4 * (16 - k)) { cum += 4 * (16 - k); ++k; }
  const int off = lid - cum;
  const int I = 4 * k + off / (16 - k);
  const int g = k + off % (16 - k);

  // staging maps (all offsets compile-time or per-lane-constant)
  const int stA_row = t >> 4, stA_kb = (t & 15) * 16;   // A: 16 rows x 16 chunks
  const int stB_row = t >> 3, stB_kb = (t & 7) * 16;    // B half: 32 rows x 8 chunks
  const int stA_h = stA_kb >> 7, stA_k = stA_kb & 127;
  // fragment read bases
  const int rdA0 = (wr * 64 + llo) * STR + lhi * 16;
  const int rdB0 = (wc * 64 + llo) * STR + lhi * 16;

  // stage A (both halves) once
#pragma unroll
  for (int it = 0; it < 8; ++it) {
    const int row = it * 16 + stA_row;
    uint4 d = *(const uint4*)(za8 + (size_t)(I * 128 + row) * 256 + stA_kb);
    *(uint4*)(ldsA + stA_h * AHALF + row * STR + stA_k) = d;
  }

  f32x4 acc[4][4];

#pragma unroll 1
  for (int c = 0; c < 4; ++c) {
    const int J = 4 * g + c;
    if (J < I) continue;                  // block-uniform skip (barrier-safe)

#pragma unroll
    for (int rt = 0; rt < 4; ++rt)
#pragma unroll
      for (int ct = 0; ct < 4; ++ct) acc[rt][ct] = (f32x4)0.0f;

#pragma unroll
    for (int h = 0; h < 2; ++h) {
      __syncthreads();                    // prior B reads (and initial A writes) done
#pragma unroll
      for (int it = 0; it < 4; ++it) {
        const int row = it * 32 + stB_row;
        uint4 d = *(const uint4*)(za8 + (size_t)(J * 128 + row) * 256 + h * 128 + stB_kb);
        *(uint4*)(ldsB + row * STR + stB_kb) = d;
      }
      __syncthreads();                    // B half visible
#pragma unroll
      for (int ks = 0; ks < 2; ++ks) {
        bf16x8 af[4], bfr[4];
#pragma unroll
        for (int rt = 0; rt < 4; ++rt)
          af[rt] = *(const bf16x8*)(ldsA + h * AHALF + rdA0 + rt * 16 * STR + ks * 64);
#pragma unroll
        for (int ct = 0; ct < 4; ++ct)
          bfr[ct] = *(const bf16x8*)(ldsB + rdB0 + ct * 16 * STR + ks * 64);
#pragma unroll
        for (int rt = 0; rt < 4; ++rt)
#pragma unroll
          for (int ct = 0; ct < 4; ++ct)
            acc[rt][ct] = __builtin_amdgcn_mfma_f32_16x16x32_bf16(
                af[rt], bfr[ct], acc[rt][ct], 0, 0, 0);
      }
    }

    // aug-positive extraction: chunks with J-I == 32 hold col == row + BATCH (lc == lr)
    if (J - I == 32) {
      float ap = 0.0f;
#pragma unroll
      for (int rt = 0; rt < 4; ++rt) {
        const int lrb = wr * 64 + rt * 16 + lhi * 4;
#pragma unroll
        for (int ct = 0; ct < 4; ++ct) {
          const int lc = wc * 64 + ct * 16 + llo;
#pragma unroll
          for (int gg = 0; gg < 4; ++gg)
            if (lc == lrb + gg) ap += acc[rt][ct][gg];
        }
      }
#pragma unroll
      for (int m = 1; m < 64; m <<= 1) ap += __shfl_xor(ap, m, 64);
      if (lane == 0) atomicAdd(augacc, ap);
    }

    // epilogue: exp2 (+ diag mask only when I==J), per-chunk row/col partials -> sc
    float cp[4] = {0.0f, 0.0f, 0.0f, 0.0f};
#pragma unroll
    for (int rt = 0; rt < 4; ++rt) {
      const int lrowb = wr * 64 + rt * 16 + lhi * 4;
      float rp[4] = {0.0f, 0.0f, 0.0f, 0.0f};
      if (I == J) {                        // block-uniform branch
#pragma unroll
        for (int ct = 0; ct < 4; ++ct) {
          const int lcol = wc * 64 + ct * 16 + llo;
#pragma unroll
          for (int gg = 0; gg < 4; ++gg) {
            float e = fast_exp2(acc[rt][ct][gg]);
            e = (lcol > lrowb + gg) ? e : 0.0f;   // strict upper triangle
            rp[gg] += e;
            cp[ct] += e;
          }
        }
      } else {
#pragma unroll
        for (int ct = 0; ct < 4; ++ct)
#pragma unroll
          for (int gg = 0; gg < 4; ++gg) {
            float e = fast_exp2(acc[rt][ct][gg]);
            rp[gg] += e;
            cp[ct] += e;
          }
      }
#pragma unroll
      for (int gg = 0; gg < 4; ++gg) {
        float s = rp[gg];
        s += __shfl_xor(s, 1, 64);
        s += __shfl_xor(s, 2, 64);
        s += __shfl_xor(s, 4, 64);
        s += __shfl_xor(s, 8, 64);
        if (llo == 0) sc_row[wc][lrowb + gg] = s;
      }
    }
#pragma unroll
    for (int ct = 0; ct < 4; ++ct) {
      float s = cp[ct];
      s += __shfl_xor(s, 16, 64);
      s += __shfl_xor(s, 32, 64);
      if (lhi == 0) sc_col[wr][wc * 64 + ct * 16 + llo] = s;
    }
    __syncthreads();                      // sc visible
    if (t < 128)
      part_row[(size_t)(I * 64 + J) * 128 + t] = sc_row[0][t] + sc_row[1][t];
    else
      part_col[(size_t)(J * 64 + I) * 128 + (t - 128)] =
          sc_col[0][t - 128] + sc_col[1][t - 128];
    // next chunk's first barrier orders these reads vs. the next epilogue's writes
  }

  // ---- fused nearby positives: 512 of the blocks, 64 dots each (16/wave, 4-lane groups) ----
  if (lid < 512) {
    const int sub = lane & 3;
    const int kk = lid * 64 + w * 16 + (lane >> 2);
    int zr, zc;
    if (kk < BATCH)                { zr = BATCH + kk; zc = kk; }
    else if (kk < BATCH + TWO_B)   { int q = kk - BATCH;             zr = q; zc = q; }
    else if (kk < BATCH + 2*TWO_B) { int q = kk - BATCH - TWO_B;     zr = q; zc = q + BATCH; }
    else if (kk < BATCH + 3*TWO_B) { int q = kk - BATCH - 2*TWO_B;   zr = q; zc = q + 2*BATCH; }
    else                           { int q = kk - BATCH - 3*TWO_B;   zr = q; zc = q + 3*BATCH; }
    const uint4* aro = (const uint4*)(za_n + (size_t)zr * DIM);   // 16 chunks of 8 bf16
    const float4* bro = (const float4*)(zn + (size_t)zc * DIM);
    float d = 0.0f;
#pragma unroll
    for (int c = 0; c < 4; ++c) {
      uint4 aw = aro[sub + c * 4];
      float4 b0 = bro[(sub + c * 4) * 2];
      float4 b1 = bro[(sub + c * 4) * 2 + 1];
      float2 q2;
      q2 = bf2_to_f2(aw.x); d += q2.x * b0.x + q2.y * b0.y;
      q2 = bf2_to_f2(aw.y); d += q2.x * b0.z + q2.y * b0.w;
      q2 = bf2_to_f2(aw.z); d += q2.x * b1.x + q2.y * b1.y;
      q2 = bf2_to_f2(aw.w); d += q2.x * b1.z + q2.y * b1.w;
    }
    d += __shfl_xor(d, 1, 64);
    d += __shfl_xor(d, 2, 64);
    if (sub == 0) {
      float ds = d * inv_zn[zc] * SQRT_EXP2_SCALE;       // = sim * EXP2_SCALE
      pos_partial[kk] = fminf(ds, EXP2_SCALE) * LN2;     // = min(sim,1) * INV_TEMP
    }
  }
}

// ---------------- K3: wave-per-row-octet gather + fused final (atomicAdd out) ----------------
__global__ __launch_bounds__(256) void k_reduce(
    const float* __restrict__ part_row, const float* __restrict__ part_col,
    const float* __restrict__ pos_partial, const float* __restrict__ augacc,
    float* __restrict__ out) {
  const int w = threadIdx.x >> 6, lane = threadIdx.x & 63;
  float s = 0.0f;
#pragma unroll
  for (int i = 0; i < 8; ++i) {
    const int r = blockIdx.x * 32 + w * 8 + i;
    const int I = r >> 7, rr = r & 127;
    const size_t base = (size_t)(I * 64 + lane) * 128 + rr;
    float v = 0.0f;
    if (lane >= I) v += part_row[base];
    if (lane <= I) v += part_col[base];
#pragma unroll
    for (int m = 1; m < 64; m <<= 1) v += __shfl_xor(v, m, 64);
    if (lane == 0) {
      float tl = 8.0f * logf(v + LOSS_EPS);
      tl -= pos_partial[r];
      tl -= pos_partial[r + TWO_B];
      tl -= pos_partial[r + 2 * TWO_B];
      tl -= pos_partial[r + 3 * TWO_B];
      s += tl;
    }
  }
  __shared__ float red[4];
  if (lane == 0) red[w] = s;
  __syncthreads();
  if (threadIdx.x == 0) {
    float bs = red[0] + red[1] + red[2] + red[3];
    if (blockIdx.x == 0) bs -= 8.0f * LN2 * augacc[0];  // aug positives from gram
    atomicAdd(out, bs * (1.0f / 65536.0f));
  }
}

extern "C" void kernel_launch(void* const* d_in, const int* in_sizes, int n_in,
                              void* d_out, int out_size, void* d_ws, size_t ws_size,
                              hipStream_t stream) {
  const float* z1 = (const float*)d_in[0];
  const float* z2 = (const float*)d_in[1];
  const float* zn = (const float*)d_in[2];
  float* out = (float*)d_out;

  char* ws = (char*)d_ws;
  __hip_bfloat16* za_n = (__hip_bfloat16*)ws;                  // 2 MB
  float* inv_zn      = (float*)(ws + 2097152);                 // 64 KB
  float* pos_partial = (float*)(ws + 2097152 + 65536);         // 128 KB
  float* augacc      = (float*)(ws + 2097152 + 65536 + 131072);          // 4 KB slot
  float* part_row    = (float*)(ws + 2097152 + 65536 + 131072 + 4096);   // 2 MB
  float* part_col    = (float*)(ws + 2097152 + 65536 + 131072 + 4096 + 2097152); // 2 MB

  // K1: normalize + zero augacc/out
  k_normalize<<<(TWO_B + NB) / 4, 256, 0, stream>>>(z1, z2, zn, za_n, inv_zn, augacc, out);
  // K2: A-reuse symmetric gram partials + fused nearby positives
  k_gram<<<GRAM_BLOCKS, 256, 0, stream>>>(za_n, zn, inv_zn, part_row, part_col,
                                          pos_partial, augacc);
  // K3: gather/log/subtract + fused final scalar
  k_reduce<<<256, 256, 0, stream>>>(part_row, part_col, pos_partial, augacc, out);
}

// Round 15
// 53.792 us; speedup vs baseline: 1.6643x; 1.2671x over previous
//
#include <hip/hip_runtime.h>
#include <hip/hip_bf16.h>
#include <math.h>

#define BATCH 4096
#define TWO_B 8192
#define DIM 128
#define NB 16384
#define COS_EPS 1e-8f
#define LOSS_EPS 1e-6f
// 1/TEMP ; log2(e)/TEMP ; sqrt(log2(e)/TEMP) ; ln 2
#define INV_TEMP 14.285714285714286f
#define EXP2_SCALE 20.60992915555662f
#define SQRT_EXP2_SCALE 4.5398166f
#define LN2 0.6931471805599453f

#define N_NEAR 32768
#define GRAM_BLOCKS 4160            // #{(I<64, J2<128): J2 >= 2I}
#define STR 144                     // half-K row: 128 B data + 16 B pad (2-way banks, imm offsets)

typedef __attribute__((ext_vector_type(8))) short bf16x8;
typedef __attribute__((ext_vector_type(4))) float f32x4;

__device__ __forceinline__ float fast_exp2(float x) {
#if __has_builtin(__builtin_amdgcn_exp2f)
  return __builtin_amdgcn_exp2f(x);
#else
  float r;
  asm("v_exp_f32 %0, %1" : "=v"(r) : "v"(x));
  return r;
#endif
}

__device__ __forceinline__ float2 bf2_to_f2(unsigned int w) {
  float2 r;
  r.x = __uint_as_float(w << 16);
  r.y = __uint_as_float(w & 0xffff0000u);
  return r;
}

// ---------------- K1: normalize za rows -> bf16 za_n (pre-scaled); inv_zn; zero augacc/out ----------------
__global__ __launch_bounds__(256) void k_normalize(
    const float* __restrict__ z1, const float* __restrict__ z2,
    const float* __restrict__ zn,
    __hip_bfloat16* __restrict__ za_n, float* __restrict__ inv_zn,
    float* __restrict__ augacc, float* __restrict__ out) {
  if (blockIdx.x == 0 && threadIdx.x == 0) { augacc[0] = 0.0f; out[0] = 0.0f; }
  int wave = (blockIdx.x * blockDim.x + threadIdx.x) >> 6;
  int lane = threadIdx.x & 63;
  if (wave >= TWO_B + NB) return;
  const float* src;
  if (wave < BATCH) src = z1 + (size_t)wave * DIM;
  else if (wave < TWO_B) src = z2 + (size_t)(wave - BATCH) * DIM;
  else src = zn + (size_t)(wave - TWO_B) * DIM;
  float2 v = ((const float2*)src)[lane];
  float ss = v.x * v.x + v.y * v.y;
#pragma unroll
  for (int m = 1; m < 64; m <<= 1) ss += __shfl_xor(ss, m, 64);
  float inv = 1.0f / fmaxf(sqrtf(ss), COS_EPS);
  if (wave < TWO_B) {
    float s = inv * SQRT_EXP2_SCALE;   // fold exp2 scale into the data
    __hip_bfloat162 o;
    o.x = __float2bfloat16(v.x * s);
    o.y = __float2bfloat16(v.y * s);
    ((__hip_bfloat162*)(za_n + (size_t)wave * DIM))[lane] = o;
  } else {
    if (lane == 0) inv_zn[wave - TWO_B] = inv;
  }
}

// ---------------- K2: symmetric Gram, 128x64 tiles (J2 >= 2I), small-footprint blocks ----------------
// 4160 blocks; 4 waves, wave-tile 64x32 (acc 32 VGPR); LDS 29.2 KB -> 5 blocks/CU.
// Same phase structure / padding / masks as the proven R11 kernel.
__global__ __launch_bounds__(256) void k_gram(
    const __hip_bfloat16* __restrict__ za_n, const float* __restrict__ zn,
    const float* __restrict__ inv_zn,
    float* __restrict__ part_row, float* __restrict__ part_col,
    float* __restrict__ pos_partial, float* __restrict__ augacc) {
  __shared__ char ldsA[128 * STR];        // 18432 B (A half-K)
  __shared__ char ldsB[64 * STR];         // 9216 B (B half-K)
  __shared__ float sc_row[2][128];        // [wc][local row]
  __shared__ float sc_col[2][64];         // [wr][local col]
  const int t = threadIdx.x;
  int rem = blockIdx.x, I = 0;
  while (rem >= 128 - 2 * I) { rem -= 128 - 2 * I; ++I; }
  const int J2 = 2 * I + rem;             // col tile of 64
  const int Ibase = I * 128, Jbase = J2 * 64;
  const char* za8 = (const char*)za_n;    // row stride 256 B

  const int w = t >> 6, lane = t & 63;
  const int wr = w & 1, wc = w >> 1;      // rows wr*64, cols wc*32
  const int lhi = lane >> 4, llo = lane & 15;

  // staging map: thread t -> row (it*32 + t>>3), 16B chunk (t&7)
  const int st_row = t >> 3, st_kb = (t & 7) * 16;
  // fragment read bases (immediate offsets elsewhere)
  const int rdA0 = (wr * 64 + llo) * STR + lhi * 16;
  const int rdB0 = (wc * 32 + llo) * STR + lhi * 16;

  f32x4 acc[4][2];
#pragma unroll
  for (int rt = 0; rt < 4; ++rt)
#pragma unroll
    for (int ct = 0; ct < 2; ++ct) acc[rt][ct] = (f32x4)0.0f;

#pragma unroll
  for (int h = 0; h < 2; ++h) {
    if (h) __syncthreads();               // half-0 reads done before overwrite
    // stage A half: 128 rows x 128 B
#pragma unroll
    for (int it = 0; it < 4; ++it) {
      const int row = it * 32 + st_row;
      uint4 d = *(const uint4*)(za8 + (size_t)(Ibase + row) * 256 + h * 128 + st_kb);
      *(uint4*)(ldsA + row * STR + st_kb) = d;
    }
    // stage B half: 64 rows x 128 B
#pragma unroll
    for (int it = 0; it < 2; ++it) {
      const int row = it * 32 + st_row;
      uint4 d = *(const uint4*)(za8 + (size_t)(Jbase + row) * 256 + h * 128 + st_kb);
      *(uint4*)(ldsB + row * STR + st_kb) = d;
    }
    __syncthreads();
#pragma unroll
    for (int ks = 0; ks < 2; ++ks) {
      bf16x8 af[4], bf[2];
#pragma unroll
      for (int rt = 0; rt < 4; ++rt)
        af[rt] = *(const bf16x8*)(ldsA + rdA0 + rt * 16 * STR + ks * 64);
#pragma unroll
      for (int ct = 0; ct < 2; ++ct)
        bf[ct] = *(const bf16x8*)(ldsB + rdB0 + ct * 16 * STR + ks * 64);
#pragma unroll
      for (int rt = 0; rt < 4; ++rt)
#pragma unroll
        for (int ct = 0; ct < 2; ++ct)
          acc[rt][ct] = __builtin_amdgcn_mfma_f32_16x16x32_bf16(
              af[rt], bf[ct], acc[rt][ct], 0, 0, 0);
    }
  }

  // aug-positive extraction: gcol == grow + BATCH occurs in tiles J2-2I in {64, 65}
  const int dJ = J2 - 2 * I;
  if (dJ == 64 || dJ == 65) {
    float ap = 0.0f;
#pragma unroll
    for (int rt = 0; rt < 4; ++rt) {
      const int growb = Ibase + wr * 64 + rt * 16 + lhi * 4;
#pragma unroll
      for (int ct = 0; ct < 2; ++ct) {
        const int gcol = Jbase + wc * 32 + ct * 16 + llo;
#pragma unroll
        for (int g = 0; g < 4; ++g)
          if (gcol == growb + g + BATCH) ap += acc[rt][ct][g];
      }
    }
#pragma unroll
    for (int m = 1; m < 64; m <<= 1) ap += __shfl_xor(ap, m, 64);
    if (lane == 0) atomicAdd(augacc, ap);
  }

  // epilogue: exp2 (+ strict-upper mask only on diagonal-straddling tiles dJ<=1)
  const bool need_mask = (dJ <= 1);       // block-uniform
  float cp[2] = {0.0f, 0.0f};
#pragma unroll
  for (int rt = 0; rt < 4; ++rt) {
    const int lrowb = wr * 64 + rt * 16 + lhi * 4;           // + g (local row)
    const int growb = Ibase + lrowb;
    float rp[4] = {0.0f, 0.0f, 0.0f, 0.0f};
    if (need_mask) {
#pragma unroll
      for (int ct = 0; ct < 2; ++ct) {
        const int gcol = Jbase + wc * 32 + ct * 16 + llo;
#pragma unroll
        for (int g = 0; g < 4; ++g) {
          float e = fast_exp2(acc[rt][ct][g]);
          e = (gcol > growb + g) ? e : 0.0f;   // strict upper triangle
          rp[g] += e;
          cp[ct] += e;
        }
      }
    } else {
#pragma unroll
      for (int ct = 0; ct < 2; ++ct)
#pragma unroll
        for (int g = 0; g < 4; ++g) {
          float e = fast_exp2(acc[rt][ct][g]);
          rp[g] += e;
          cp[ct] += e;
        }
    }
#pragma unroll
    for (int g = 0; g < 4; ++g) {
      float s = rp[g];
      s += __shfl_xor(s, 1, 64);
      s += __shfl_xor(s, 2, 64);
      s += __shfl_xor(s, 4, 64);
      s += __shfl_xor(s, 8, 64);
      if (llo == 0) sc_row[wc][lrowb + g] = s;
    }
  }
#pragma unroll
  for (int ct = 0; ct < 2; ++ct) {
    float s = cp[ct];
    s += __shfl_xor(s, 16, 64);
    s += __shfl_xor(s, 32, 64);
    if (lhi == 0) sc_col[wr][wc * 32 + ct * 16 + llo] = s;
  }
  __syncthreads();
  if (t < 128)
    part_row[((size_t)I * 128 + J2) * 128 + t] = sc_row[0][t] + sc_row[1][t];
  else if (t < 192)
    part_col[((size_t)J2 * 64 + I) * 64 + (t - 128)] =
        sc_col[0][t - 128] + sc_col[1][t - 128];

  // ---- fused nearby positives: blocks 0..511, 64 dots each (16/wave, 4-lane groups) ----
  if (blockIdx.x < 512) {
    const int sub = lane & 3;
    const int k = blockIdx.x * 64 + w * 16 + (lane >> 2);
    int zr, zc;
    if (k < BATCH)                { zr = BATCH + k; zc = k; }
    else if (k < BATCH + TWO_B)   { int q = k - BATCH;             zr = q; zc = q; }
    else if (k < BATCH + 2*TWO_B) { int q = k - BATCH - TWO_B;     zr = q; zc = q + BATCH; }
    else if (k < BATCH + 3*TWO_B) { int q = k - BATCH - 2*TWO_B;   zr = q; zc = q + 2*BATCH; }
    else                          { int q = k - BATCH - 3*TWO_B;   zr = q; zc = q + 3*BATCH; }
    const uint4* aro = (const uint4*)(za_n + (size_t)zr * DIM);   // 16 chunks of 8 bf16
    const float4* bro = (const float4*)(zn + (size_t)zc * DIM);
    float d = 0.0f;
#pragma unroll
    for (int c = 0; c < 4; ++c) {
      uint4 aw = aro[sub + c * 4];
      float4 b0 = bro[(sub + c * 4) * 2];
      float4 b1 = bro[(sub + c * 4) * 2 + 1];
      float2 q2;
      q2 = bf2_to_f2(aw.x); d += q2.x * b0.x + q2.y * b0.y;
      q2 = bf2_to_f2(aw.y); d += q2.x * b0.z + q2.y * b0.w;
      q2 = bf2_to_f2(aw.z); d += q2.x * b1.x + q2.y * b1.y;
      q2 = bf2_to_f2(aw.w); d += q2.x * b1.z + q2.y * b1.w;
    }
    d += __shfl_xor(d, 1, 64);
    d += __shfl_xor(d, 2, 64);
    if (sub == 0) {
      float ds = d * inv_zn[zc] * SQRT_EXP2_SCALE;       // = sim * EXP2_SCALE
      pos_partial[k] = fminf(ds, EXP2_SCALE) * LN2;      // = min(sim,1) * INV_TEMP
    }
  }
}

// ---------------- K3: wave-per-row-octet gather (3 gated loads/lane) + fused final ----------------
__global__ __launch_bounds__(256) void k_reduce(
    const float* __restrict__ part_row, const float* __restrict__ part_col,
    const float* __restrict__ pos_partial, const float* __restrict__ augacc,
    float* __restrict__ out) {
  const int w = threadIdx.x >> 6, lane = threadIdx.x & 63;
  float s = 0.0f;
#pragma unroll
  for (int i = 0; i < 8; ++i) {
    const int r = blockIdx.x * 32 + w * 8 + i;
    const int I = r >> 7, rr = r & 127;
    const int J2c = r >> 6, cc = r & 63;
    float v = 0.0f;
    // row-sum tiles J2 in [2I, 128)
    const int J2a = 2 * I + lane;
    if (J2a < 128) v += part_row[((size_t)I * 128 + J2a) * 128 + rr];
    const int J2b = 2 * I + 64 + lane;
    if (J2b < 128) v += part_row[((size_t)I * 128 + J2b) * 128 + rr];
    // col-sum tiles (I2, J2c) with 2*I2 <= J2c
    if (lane <= (J2c >> 1)) v += part_col[((size_t)J2c * 64 + lane) * 64 + cc];
#pragma unroll
    for (int m = 1; m < 64; m <<= 1) v += __shfl_xor(v, m, 64);
    if (lane == 0) {
      float tl = 8.0f * logf(v + LOSS_EPS);
      tl -= pos_partial[r];
      tl -= pos_partial[r + TWO_B];
      tl -= pos_partial[r + 2 * TWO_B];
      tl -= pos_partial[r + 3 * TWO_B];
      s += tl;
    }
  }
  __shared__ float red[4];
  if (lane == 0) red[w] = s;
  __syncthreads();
  if (threadIdx.x == 0) {
    float bs = red[0] + red[1] + red[2] + red[3];
    if (blockIdx.x == 0) bs -= 8.0f * LN2 * augacc[0];  // aug positives from gram
    atomicAdd(out, bs * (1.0f / 65536.0f));
  }
}

extern "C" void kernel_launch(void* const* d_in, const int* in_sizes, int n_in,
                              void* d_out, int out_size, void* d_ws, size_t ws_size,
                              hipStream_t stream) {
  const float* z1 = (const float*)d_in[0];
  const float* z2 = (const float*)d_in[1];
  const float* zn = (const float*)d_in[2];
  float* out = (float*)d_out;

  char* ws = (char*)d_ws;
  __hip_bfloat16* za_n = (__hip_bfloat16*)ws;                  // 2 MB
  float* inv_zn      = (float*)(ws + 2097152);                 // 64 KB
  float* pos_partial = (float*)(ws + 2097152 + 65536);         // 128 KB
  float* augacc      = (float*)(ws + 2097152 + 65536 + 131072);          // 4 KB slot
  float* part_row    = (float*)(ws + 2097152 + 65536 + 131072 + 4096);   // 4 MB
  float* part_col    = (float*)(ws + 2097152 + 65536 + 131072 + 4096 + 4194304); // 2 MB

  // K1: normalize + zero augacc/out
  k_normalize<<<(TWO_B + NB) / 4, 256, 0, stream>>>(z1, z2, zn, za_n, inv_zn, augacc, out);
  // K2: small-footprint symmetric gram partials + fused nearby positives
  k_gram<<<GRAM_BLOCKS, 256, 0, stream>>>(za_n, zn, inv_zn, part_row, part_col,
                                          pos_partial, augacc);
  // K3: gather/log/subtract + fused final scalar
  k_reduce<<<256, 256, 0, stream>>>(part_row, part_col, pos_partial, augacc, out);
}

// Round 16
// 44.808 us; speedup vs baseline: 1.9981x; 1.2005x over previous
//
#include <hip/hip_runtime.h>
#include <hip/hip_bf16.h>
#include <math.h>

#define BATCH 4096
#define TWO_B 8192
#define DIM 128
#define NB 16384
#define COS_EPS 1e-8f
#define LOSS_EPS 1e-6f
// 1/TEMP ; log2(e)/TEMP ; sqrt(log2(e)/TEMP) ; ln 2
#define INV_TEMP 14.285714285714286f
#define EXP2_SCALE 20.60992915555662f
#define SQRT_EXP2_SCALE 4.5398166f
#define LN2 0.6931471805599453f

#define N_NEAR 32768                // nearby positive dots
#define GRAM_BLOCKS 2080            // #{(I,J): 0<=I<=J<64}
#define STR 144                     // half-K row: 128 B data + 16 B pad (R11-proven)

typedef __attribute__((ext_vector_type(8))) short bf16x8;
typedef __attribute__((ext_vector_type(4))) float f32x4;

__device__ __forceinline__ float fast_exp2(float x) {
#if __has_builtin(__builtin_amdgcn_exp2f)
  return __builtin_amdgcn_exp2f(x);
#else
  float r;
  asm("v_exp_f32 %0, %1" : "=v"(r) : "v"(x));
  return r;
#endif
}

__device__ __forceinline__ float2 bf2_to_f2(unsigned int w) {
  float2 r;
  r.x = __uint_as_float(w << 16);
  r.y = __uint_as_float(w & 0xffff0000u);
  return r;
}

// RNE float->bf16 (inputs bounded, no NaN/Inf path needed)
__device__ __forceinline__ unsigned short f2bf(float f) {
  unsigned int u = __float_as_uint(f);
  return (unsigned short)((u + 0x7fffu + ((u >> 16) & 1u)) >> 16);
}

// ---------------- K1: normalize, one wave per 2 rows (float4 loads); zero augacc/out ----------------
__global__ __launch_bounds__(256) void k_normalize(
    const float* __restrict__ z1, const float* __restrict__ z2,
    const float* __restrict__ zn,
    __hip_bfloat16* __restrict__ za_n, float* __restrict__ inv_zn,
    float* __restrict__ augacc, float* __restrict__ out) {
  if (blockIdx.x == 0 && threadIdx.x == 0) { augacc[0] = 0.0f; out[0] = 0.0f; }
  const int wave = (blockIdx.x * blockDim.x + threadIdx.x) >> 6;
  const int lane = threadIdx.x & 63;
  const int row = wave * 2 + (lane >> 5);        // each 32-lane half owns one row
  const int e = lane & 31;                       // float4 slot within row
  if (row >= TWO_B + NB) return;
  const float* src;
  if (row < BATCH) src = z1 + (size_t)row * DIM;
  else if (row < TWO_B) src = z2 + (size_t)(row - BATCH) * DIM;
  else src = zn + (size_t)(row - TWO_B) * DIM;
  float4 v = ((const float4*)src)[e];
  float ss = v.x * v.x + v.y * v.y + v.z * v.z + v.w * v.w;
#pragma unroll
  for (int m = 1; m < 32; m <<= 1) ss += __shfl_xor(ss, m, 64);  // within 32-half
  float inv = 1.0f / fmaxf(sqrtf(ss), COS_EPS);
  if (row < TWO_B) {
    const float s = inv * SQRT_EXP2_SCALE;       // fold exp2 scale into the data
    ushort4 o;
    o.x = f2bf(v.x * s);
    o.y = f2bf(v.y * s);
    o.z = f2bf(v.z * s);
    o.w = f2bf(v.w * s);
    ((ushort4*)(za_n + (size_t)row * DIM))[e] = o;
  } else if (e == 0) {
    inv_zn[row - TWO_B] = inv;
  }
}

// ---------------- K2: symmetric Gram, 128x128 tiles (I<=J), padded LDS, fused positives ----------------
// grid: 2080 blocks; block 256 thr = 4 waves of 64x64; LDS 36.9 KB (K split in 2 halves) -> 4 blocks/CU.
// Padded rows (stride 144 B): conflict-free ds access, ds_read addresses are base+immediate.
__global__ __launch_bounds__(256) void k_gram(
    const __hip_bfloat16* __restrict__ za_n, const float* __restrict__ zn,
    const float* __restrict__ inv_zn,
    float* __restrict__ part_row, float* __restrict__ part_col,
    float* __restrict__ pos_partial, float* __restrict__ augacc) {
  __shared__ char lds[2 * 128 * STR];   // A then B
  char* ldsA = lds;
  char* ldsB = lds + 128 * STR;
  const int t = threadIdx.x;
  int rem = blockIdx.x, I = 0;
  while (rem >= 64 - I) { rem -= 64 - I; ++I; }
  const int J = I + rem;
  const int Ibase = I * 128, Jbase = J * 128;
  const char* za8 = (const char*)za_n;   // byte view; row stride 256 B

  const int w = t >> 6, lane = t & 63;
  const int wr = w & 1, wc = w >> 1;     // 2x2 waves of 64x64
  const int lhi = lane >> 4, llo = lane & 15;

  // precomputed per-lane LDS bases (fragment reads use base + compile-time offsets)
  const int rdA0 = (wr * 64 + llo) * STR + lhi * 16;
  const int rdB0 = (wc * 64 + llo) * STR + lhi * 16;
  // staging: thread t writes rows (it*32 + t>>3), 16B chunk (t&7)
  const int st_row = t >> 3, st_kb = (t & 7) * 16;
  const int st_lds = st_row * STR + st_kb;

  f32x4 acc[4][4];
#pragma unroll
  for (int rt = 0; rt < 4; ++rt)
#pragma unroll
    for (int ct = 0; ct < 4; ++ct) acc[rt][ct] = (f32x4)0.0f;

  for (int h = 0; h < 2; ++h) {
    if (h) __syncthreads();              // half-0 reads complete before overwrite
#pragma unroll
    for (int it = 0; it < 4; ++it) {
      uint4 d = *(const uint4*)(za8 + (size_t)(Ibase + it * 32 + st_row) * 256 + h * 128 + st_kb);
      *(uint4*)(ldsA + it * 32 * STR + st_lds) = d;
    }
#pragma unroll
    for (int it = 0; it < 4; ++it) {
      uint4 d = *(const uint4*)(za8 + (size_t)(Jbase + it * 32 + st_row) * 256 + h * 128 + st_kb);
      *(uint4*)(ldsB + it * 32 * STR + st_lds) = d;
    }
    __syncthreads();
#pragma unroll
    for (int ks = 0; ks < 2; ++ks) {
      bf16x8 af[4], bfr[4];
#pragma unroll
      for (int rt = 0; rt < 4; ++rt)
        af[rt] = *(const bf16x8*)(ldsA + rdA0 + rt * 16 * STR + ks * 64);
#pragma unroll
      for (int ct = 0; ct < 4; ++ct)
        bfr[ct] = *(const bf16x8*)(ldsB + rdB0 + ct * 16 * STR + ks * 64);
      __builtin_amdgcn_s_setprio(1);
#pragma unroll
      for (int rt = 0; rt < 4; ++rt)
#pragma unroll
        for (int ct = 0; ct < 4; ++ct)
          acc[rt][ct] = __builtin_amdgcn_mfma_f32_16x16x32_bf16(
              af[rt], bfr[ct], acc[rt][ct], 0, 0, 0);
      __builtin_amdgcn_s_setprio(0);
    }
  }

  // aug-positive extraction: cells with col == row + BATCH live in tiles J-I == 32 (lc == lr)
  if (J - I == 32) {
    float ap = 0.0f;
#pragma unroll
    for (int rt = 0; rt < 4; ++rt) {
      const int lrb = wr * 64 + rt * 16 + lhi * 4;
#pragma unroll
      for (int ct = 0; ct < 4; ++ct) {
        const int lc = wc * 64 + ct * 16 + llo;
#pragma unroll
        for (int g = 0; g < 4; ++g)
          if (lc == lrb + g) ap += acc[rt][ct][g];
      }
    }
#pragma unroll
    for (int m = 1; m < 64; m <<= 1) ap += __shfl_xor(ap, m, 64);
    if (lane == 0) atomicAdd(augacc, ap);
  }

  // epilogue: exp2 (+ diag mask only on I==J blocks); per-block row/col partials in LDS
  __syncthreads();                        // all MFMA LDS reads done; safe to alias lds
  float* lds_row = (float*)lds;           // [2][128] indexed [wc][localrow]
  float* lds_col = (float*)(lds + 1024);  // [2][128] indexed [wr][localcol]

  float cp[4] = {0.0f, 0.0f, 0.0f, 0.0f};
#pragma unroll
  for (int rt = 0; rt < 4; ++rt) {
    const int lrowb = wr * 64 + rt * 16 + lhi * 4;           // + g (local row)
    float rp[4] = {0.0f, 0.0f, 0.0f, 0.0f};
    if (I == J) {                          // block-uniform branch
#pragma unroll
      for (int ct = 0; ct < 4; ++ct) {
        const int lcol = wc * 64 + ct * 16 + llo;
#pragma unroll
        for (int g = 0; g < 4; ++g) {
          float e = fast_exp2(acc[rt][ct][g]);
          e = (lcol > lrowb + g) ? e : 0.0f;   // strict upper triangle
          rp[g] += e;
          cp[ct] += e;
        }
      }
    } else {
#pragma unroll
      for (int ct = 0; ct < 4; ++ct)
#pragma unroll
        for (int g = 0; g < 4; ++g) {
          float e = fast_exp2(acc[rt][ct][g]);
          rp[g] += e;
          cp[ct] += e;
        }
    }
#pragma unroll
    for (int g = 0; g < 4; ++g) {
      float s = rp[g];
      s += __shfl_xor(s, 1, 64);
      s += __shfl_xor(s, 2, 64);
      s += __shfl_xor(s, 4, 64);
      s += __shfl_xor(s, 8, 64);
      if (llo == 0) lds_row[wc * 128 + lrowb + g] = s;
    }
  }
#pragma unroll
  for (int ct = 0; ct < 4; ++ct) {
    float s = cp[ct];
    s += __shfl_xor(s, 16, 64);
    s += __shfl_xor(s, 32, 64);
    if (lhi == 0) lds_col[wr * 128 + wc * 64 + ct * 16 + llo] = s;
  }
  __syncthreads();
  if (t < 128)
    part_row[(size_t)(I * 64 + J) * 128 + t] = lds_row[t] + lds_row[128 + t];
  else
    part_col[(size_t)(J * 64 + I) * 128 + (t - 128)] =
        lds_col[t - 128] + lds_col[t];

  // ---- fused nearby positives: blocks 0..1023, 32 dots each (4 waves x 8) ----
  if (blockIdx.x < N_NEAR / 32) {
    const int sub = lane & 7;
    const int k = blockIdx.x * 32 + w * 8 + (lane >> 3);
    int zr, zc;
    if (k < BATCH)                { zr = BATCH + k; zc = k; }
    else if (k < BATCH + TWO_B)   { int q = k - BATCH;             zr = q; zc = q; }
    else if (k < BATCH + 2*TWO_B) { int q = k - BATCH - TWO_B;     zr = q; zc = q + BATCH; }
    else if (k < BATCH + 3*TWO_B) { int q = k - BATCH - 2*TWO_B;   zr = q; zc = q + 2*BATCH; }
    else                          { int q = k - BATCH - 3*TWO_B;   zr = q; zc = q + 3*BATCH; }
    const uint4* aro = (const uint4*)(za_n + (size_t)zr * DIM);    // 16B = 8 bf16
    const float4* bro = (const float4*)(zn + (size_t)zc * DIM);
    float d = 0.0f;
#pragma unroll
    for (int c = 0; c < 2; ++c) {
      uint4 aw = aro[sub * 2 + c];
      float4 b0 = bro[sub * 4 + c * 2];
      float4 b1 = bro[sub * 4 + c * 2 + 1];
      float2 q2;
      q2 = bf2_to_f2(aw.x); d += q2.x * b0.x + q2.y * b0.y;
      q2 = bf2_to_f2(aw.y); d += q2.x * b0.z + q2.y * b0.w;
      q2 = bf2_to_f2(aw.z); d += q2.x * b1.x + q2.y * b1.y;
      q2 = bf2_to_f2(aw.w); d += q2.x * b1.z + q2.y * b1.w;
    }
    d += __shfl_xor(d, 1, 64);
    d += __shfl_xor(d, 2, 64);
    d += __shfl_xor(d, 4, 64);
    if (sub == 0) {
      float ds = d * inv_zn[zc] * SQRT_EXP2_SCALE;       // = sim * EXP2_SCALE
      pos_partial[k] = fminf(ds, EXP2_SCALE) * LN2;      // = min(sim,1) * INV_TEMP
    }
  }
}

// ---------------- K3: wave-per-row-octet gather + fused final (atomicAdd out) ----------------
__global__ __launch_bounds__(256) void k_reduce(
    const float* __restrict__ part_row, const float* __restrict__ part_col,
    const float* __restrict__ pos_partial, const float* __restrict__ augacc,
    float* __restrict__ out) {
  const int w = threadIdx.x >> 6, lane = threadIdx.x & 63;
  float s = 0.0f;
#pragma unroll
  for (int i = 0; i < 8; ++i) {
    const int r = blockIdx.x * 32 + w * 8 + i;
    const int I = r >> 7, rr = r & 127;
    const size_t base = (size_t)(I * 64 + lane) * 128 + rr;
    float v = 0.0f;
    if (lane >= I) v += part_row[base];
    if (lane <= I) v += part_col[base];
#pragma unroll
    for (int m = 1; m < 64; m <<= 1) v += __shfl_xor(v, m, 64);
    if (lane == 0) {
      float tl = 8.0f * logf(v + LOSS_EPS);
      tl -= pos_partial[r];
      tl -= pos_partial[r + TWO_B];
      tl -= pos_partial[r + 2 * TWO_B];
      tl -= pos_partial[r + 3 * TWO_B];
      s += tl;
    }
  }
  __shared__ float red[4];
  if (lane == 0) red[w] = s;
  __syncthreads();
  if (threadIdx.x == 0) {
    float bs = red[0] + red[1] + red[2] + red[3];
    if (blockIdx.x == 0) bs -= 8.0f * LN2 * augacc[0];  // aug positives from gram
    atomicAdd(out, bs * (1.0f / 65536.0f));
  }
}

extern "C" void kernel_launch(void* const* d_in, const int* in_sizes, int n_in,
                              void* d_out, int out_size, void* d_ws, size_t ws_size,
                              hipStream_t stream) {
  const float* z1 = (const float*)d_in[0];
  const float* z2 = (const float*)d_in[1];
  const float* zn = (const float*)d_in[2];
  float* out = (float*)d_out;

  char* ws = (char*)d_ws;
  __hip_bfloat16* za_n = (__hip_bfloat16*)ws;                  // 2 MB
  float* inv_zn      = (float*)(ws + 2097152);                 // 64 KB
  float* pos_partial = (float*)(ws + 2097152 + 65536);         // 128 KB
  float* augacc      = (float*)(ws + 2097152 + 65536 + 131072);          // 4 KB slot
  float* part_row    = (float*)(ws + 2097152 + 65536 + 131072 + 4096);   // 2 MB
  float* part_col    = (float*)(ws + 2097152 + 65536 + 131072 + 4096 + 2097152); // 2 MB

  // K1: normalize (1 wave / 2 rows -> 3072 blocks) + zero augacc/out
  k_normalize<<<(TWO_B + NB) / 8, 256, 0, stream>>>(z1, z2, zn, za_n, inv_zn, augacc, out);
  // K2: symmetric gram partials + fused nearby positives (R11 structure + setprio)
  k_gram<<<GRAM_BLOCKS, 256, 0, stream>>>(za_n, zn, inv_zn, part_row, part_col,
                                          pos_partial, augacc);
  // K3: gather/log/subtract + fused final scalar
  k_reduce<<<256, 256, 0, stream>>>(part_row, part_col, pos_partial, augacc, out);
}

// Round 17
// 44.618 us; speedup vs baseline: 2.0065x; 1.0042x over previous
//
#include <hip/hip_runtime.h>
#include <hip/hip_bf16.h>
#include <math.h>

#define BATCH 4096
#define TWO_B 8192
#define DIM 128
#define NB 16384
#define COS_EPS 1e-8f
#define LOSS_EPS 1e-6f
// 1/TEMP ; log2(e)/TEMP ; sqrt(log2(e)/TEMP) ; ln 2
#define INV_TEMP 14.285714285714286f
#define EXP2_SCALE 20.60992915555662f
#define SQRT_EXP2_SCALE 4.5398166f
#define LN2 0.6931471805599453f

#define N_NEAR 32768                // nearby positive dots
#define GRAM_BLOCKS 2080            // #{(I,J): 0<=I<=J<64} = 8 x 260
#define STR 144                     // half-K row: 128 B data + 16 B pad (R11-proven)

typedef __attribute__((ext_vector_type(8))) short bf16x8;
typedef __attribute__((ext_vector_type(4))) float f32x4;

__device__ __forceinline__ float fast_exp2(float x) {
#if __has_builtin(__builtin_amdgcn_exp2f)
  return __builtin_amdgcn_exp2f(x);
#else
  float r;
  asm("v_exp_f32 %0, %1" : "=v"(r) : "v"(x));
  return r;
#endif
}

__device__ __forceinline__ float2 bf2_to_f2(unsigned int w) {
  float2 r;
  r.x = __uint_as_float(w << 16);
  r.y = __uint_as_float(w & 0xffff0000u);
  return r;
}

// RNE float->bf16 (inputs bounded, no NaN/Inf path needed)
__device__ __forceinline__ unsigned short f2bf(float f) {
  unsigned int u = __float_as_uint(f);
  return (unsigned short)((u + 0x7fffu + ((u >> 16) & 1u)) >> 16);
}

// ---------------- K1: normalize, one wave per 2 rows (float4 loads); zero augacc/out ----------------
__global__ __launch_bounds__(256) void k_normalize(
    const float* __restrict__ z1, const float* __restrict__ z2,
    const float* __restrict__ zn,
    __hip_bfloat16* __restrict__ za_n, float* __restrict__ inv_zn,
    float* __restrict__ augacc, float* __restrict__ out) {
  if (blockIdx.x == 0 && threadIdx.x == 0) { augacc[0] = 0.0f; out[0] = 0.0f; }
  const int wave = (blockIdx.x * blockDim.x + threadIdx.x) >> 6;
  const int lane = threadIdx.x & 63;
  const int row = wave * 2 + (lane >> 5);        // each 32-lane half owns one row
  const int e = lane & 31;                       // float4 slot within row
  if (row >= TWO_B + NB) return;
  const float* src;
  if (row < BATCH) src = z1 + (size_t)row * DIM;
  else if (row < TWO_B) src = z2 + (size_t)(row - BATCH) * DIM;
  else src = zn + (size_t)(row - TWO_B) * DIM;
  float4 v = ((const float4*)src)[e];
  float ss = v.x * v.x + v.y * v.y + v.z * v.z + v.w * v.w;
#pragma unroll
  for (int m = 1; m < 32; m <<= 1) ss += __shfl_xor(ss, m, 64);  // within 32-half
  float inv = 1.0f / fmaxf(sqrtf(ss), COS_EPS);
  if (row < TWO_B) {
    const float s = inv * SQRT_EXP2_SCALE;       // fold exp2 scale into the data
    ushort4 o;
    o.x = f2bf(v.x * s);
    o.y = f2bf(v.y * s);
    o.z = f2bf(v.z * s);
    o.w = f2bf(v.w * s);
    ((ushort4*)(za_n + (size_t)row * DIM))[e] = o;
  } else if (e == 0) {
    inv_zn[row - TWO_B] = inv;
  }
}

// ---------------- K2: symmetric Gram, 128x128 tiles (I<=J), padded LDS, fused positives ----------------
// grid: 2080 blocks (XCD-swizzled); 4 waves of 64x64; LDS 36.9 KB -> 4 blocks/CU.
// A-half-1 prefetched into registers during half-0 compute (T14-lite).
__global__ __launch_bounds__(256) void k_gram(
    const __hip_bfloat16* __restrict__ za_n, const float* __restrict__ zn,
    const float* __restrict__ inv_zn,
    float* __restrict__ part_row, float* __restrict__ part_col,
    float* __restrict__ pos_partial, float* __restrict__ augacc) {
  __shared__ char lds[2 * 128 * STR];   // A then B
  char* ldsA = lds;
  char* ldsB = lds + 128 * STR;
  const int t = threadIdx.x;
  // XCD swizzle: 2080 = 8 x 260; consecutive lids share the A panel -> per-XCD L2 locality
  const int lid = ((int)blockIdx.x & 7) * 260 + ((int)blockIdx.x >> 3);
  int rem = lid, I = 0;
  while (rem >= 64 - I) { rem -= 64 - I; ++I; }
  const int J = I + rem;
  const int Ibase = I * 128, Jbase = J * 128;
  const char* za8 = (const char*)za_n;   // byte view; row stride 256 B

  const int w = t >> 6, lane = t & 63;
  const int wr = w & 1, wc = w >> 1;     // 2x2 waves of 64x64
  const int lhi = lane >> 4, llo = lane & 15;

  // precomputed per-lane LDS bases (fragment reads use base + compile-time offsets)
  const int rdA0 = (wr * 64 + llo) * STR + lhi * 16;
  const int rdB0 = (wc * 64 + llo) * STR + lhi * 16;
  // staging: thread t writes rows (it*32 + t>>3), 16B chunk (t&7)
  const int st_row = t >> 3, st_kb = (t & 7) * 16;
  const int st_lds = st_row * STR + st_kb;

  f32x4 acc[4][4];
#pragma unroll
  for (int rt = 0; rt < 4; ++rt)
#pragma unroll
    for (int ct = 0; ct < 4; ++ct) acc[rt][ct] = (f32x4)0.0f;

#define GRAM_COMPUTE                                                            \
  { _Pragma("unroll")                                                           \
    for (int ks = 0; ks < 2; ++ks) {                                            \
      bf16x8 af[4], bfr[4];                                                     \
      _Pragma("unroll") for (int rt = 0; rt < 4; ++rt)                          \
        af[rt] = *(const bf16x8*)(ldsA + rdA0 + rt * 16 * STR + ks * 64);       \
      _Pragma("unroll") for (int ct = 0; ct < 4; ++ct)                          \
        bfr[ct] = *(const bf16x8*)(ldsB + rdB0 + ct * 16 * STR + ks * 64);      \
      __builtin_amdgcn_s_setprio(1);                                            \
      _Pragma("unroll") for (int rt = 0; rt < 4; ++rt)                          \
        _Pragma("unroll") for (int ct = 0; ct < 4; ++ct)                        \
          acc[rt][ct] = __builtin_amdgcn_mfma_f32_16x16x32_bf16(                \
              af[rt], bfr[ct], acc[rt][ct], 0, 0, 0);                           \
      __builtin_amdgcn_s_setprio(0);                                            \
    } }

  // ---- half 0: stage A0+B0, prefetch A1 into registers ----
#pragma unroll
  for (int it = 0; it < 4; ++it) {
    uint4 d = *(const uint4*)(za8 + (size_t)(Ibase + it * 32 + st_row) * 256 + st_kb);
    *(uint4*)(ldsA + it * 32 * STR + st_lds) = d;
  }
#pragma unroll
  for (int it = 0; it < 4; ++it) {
    uint4 d = *(const uint4*)(za8 + (size_t)(Jbase + it * 32 + st_row) * 256 + st_kb);
    *(uint4*)(ldsB + it * 32 * STR + st_lds) = d;
  }
  // prefetch A half-1 (lands during half-0 compute)
  uint4 pA0 = *(const uint4*)(za8 + (size_t)(Ibase + 0 * 32 + st_row) * 256 + 128 + st_kb);
  uint4 pA1 = *(const uint4*)(za8 + (size_t)(Ibase + 1 * 32 + st_row) * 256 + 128 + st_kb);
  uint4 pA2 = *(const uint4*)(za8 + (size_t)(Ibase + 2 * 32 + st_row) * 256 + 128 + st_kb);
  uint4 pA3 = *(const uint4*)(za8 + (size_t)(Ibase + 3 * 32 + st_row) * 256 + 128 + st_kb);
  __syncthreads();

  GRAM_COMPUTE;                          // half 0

  __syncthreads();                       // half-0 reads complete before overwrite
  // ---- half 1: write prefetched A1, stage B1 ----
  *(uint4*)(ldsA + 0 * 32 * STR + st_lds) = pA0;
  *(uint4*)(ldsA + 1 * 32 * STR + st_lds) = pA1;
  *(uint4*)(ldsA + 2 * 32 * STR + st_lds) = pA2;
  *(uint4*)(ldsA + 3 * 32 * STR + st_lds) = pA3;
#pragma unroll
  for (int it = 0; it < 4; ++it) {
    uint4 d = *(const uint4*)(za8 + (size_t)(Jbase + it * 32 + st_row) * 256 + 128 + st_kb);
    *(uint4*)(ldsB + it * 32 * STR + st_lds) = d;
  }
  __syncthreads();

  GRAM_COMPUTE;                          // half 1

  // aug-positive extraction: cells with col == row + BATCH live in tiles J-I == 32 (lc == lr)
  if (J - I == 32) {
    float ap = 0.0f;
#pragma unroll
    for (int rt = 0; rt < 4; ++rt) {
      const int lrb = wr * 64 + rt * 16 + lhi * 4;
#pragma unroll
      for (int ct = 0; ct < 4; ++ct) {
        const int lc = wc * 64 + ct * 16 + llo;
#pragma unroll
        for (int g = 0; g < 4; ++g)
          if (lc == lrb + g) ap += acc[rt][ct][g];
      }
    }
#pragma unroll
    for (int m = 1; m < 64; m <<= 1) ap += __shfl_xor(ap, m, 64);
    if (lane == 0) atomicAdd(augacc, ap);
  }

  // epilogue: exp2 (+ diag mask only on I==J blocks); per-block row/col partials in LDS
  __syncthreads();                        // all MFMA LDS reads done; safe to alias lds
  float* lds_row = (float*)lds;           // [2][128] indexed [wc][localrow]
  float* lds_col = (float*)(lds + 1024);  // [2][128] indexed [wr][localcol]

  float cp[4] = {0.0f, 0.0f, 0.0f, 0.0f};
#pragma unroll
  for (int rt = 0; rt < 4; ++rt) {
    const int lrowb = wr * 64 + rt * 16 + lhi * 4;           // + g (local row)
    float rp[4] = {0.0f, 0.0f, 0.0f, 0.0f};
    if (I == J) {                          // block-uniform branch
#pragma unroll
      for (int ct = 0; ct < 4; ++ct) {
        const int lcol = wc * 64 + ct * 16 + llo;
#pragma unroll
        for (int g = 0; g < 4; ++g) {
          float e = fast_exp2(acc[rt][ct][g]);
          e = (lcol > lrowb + g) ? e : 0.0f;   // strict upper triangle
          rp[g] += e;
          cp[ct] += e;
        }
      }
    } else {
#pragma unroll
      for (int ct = 0; ct < 4; ++ct)
#pragma unroll
        for (int g = 0; g < 4; ++g) {
          float e = fast_exp2(acc[rt][ct][g]);
          rp[g] += e;
          cp[ct] += e;
        }
    }
#pragma unroll
    for (int g = 0; g < 4; ++g) {
      float s = rp[g];
      s += __shfl_xor(s, 1, 64);
      s += __shfl_xor(s, 2, 64);
      s += __shfl_xor(s, 4, 64);
      s += __shfl_xor(s, 8, 64);
      if (llo == 0) lds_row[wc * 128 + lrowb + g] = s;
    }
  }
#pragma unroll
  for (int ct = 0; ct < 4; ++ct) {
    float s = cp[ct];
    s += __shfl_xor(s, 16, 64);
    s += __shfl_xor(s, 32, 64);
    if (lhi == 0) lds_col[wr * 128 + wc * 64 + ct * 16 + llo] = s;
  }
  __syncthreads();
  if (t < 128)
    part_row[(size_t)(I * 64 + J) * 128 + t] = lds_row[t] + lds_row[128 + t];
  else
    part_col[(size_t)(J * 64 + I) * 128 + (t - 128)] =
        lds_col[t - 128] + lds_col[t];

  // ---- fused nearby positives: lids 0..1023, 32 dots each (4 waves x 8) ----
  if (lid < N_NEAR / 32) {
    const int sub = lane & 7;
    const int k = lid * 32 + w * 8 + (lane >> 3);
    int zr, zc;
    if (k < BATCH)                { zr = BATCH + k; zc = k; }
    else if (k < BATCH + TWO_B)   { int q = k - BATCH;             zr = q; zc = q; }
    else if (k < BATCH + 2*TWO_B) { int q = k - BATCH - TWO_B;     zr = q; zc = q + BATCH; }
    else if (k < BATCH + 3*TWO_B) { int q = k - BATCH - 2*TWO_B;   zr = q; zc = q + 2*BATCH; }
    else                          { int q = k - BATCH - 3*TWO_B;   zr = q; zc = q + 3*BATCH; }
    const uint4* aro = (const uint4*)(za_n + (size_t)zr * DIM);    // 16B = 8 bf16
    const float4* bro = (const float4*)(zn + (size_t)zc * DIM);
    float d = 0.0f;
#pragma unroll
    for (int c = 0; c < 2; ++c) {
      uint4 aw = aro[sub * 2 + c];
      float4 b0 = bro[sub * 4 + c * 2];
      float4 b1 = bro[sub * 4 + c * 2 + 1];
      float2 q2;
      q2 = bf2_to_f2(aw.x); d += q2.x * b0.x + q2.y * b0.y;
      q2 = bf2_to_f2(aw.y); d += q2.x * b0.z + q2.y * b0.w;
      q2 = bf2_to_f2(aw.z); d += q2.x * b1.x + q2.y * b1.y;
      q2 = bf2_to_f2(aw.w); d += q2.x * b1.z + q2.y * b1.w;
    }
    d += __shfl_xor(d, 1, 64);
    d += __shfl_xor(d, 2, 64);
    d += __shfl_xor(d, 4, 64);
    if (sub == 0) {
      float ds = d * inv_zn[zc] * SQRT_EXP2_SCALE;       // = sim * EXP2_SCALE
      pos_partial[k] = fminf(ds, EXP2_SCALE) * LN2;      // = min(sim,1) * INV_TEMP
    }
  }
}

// ---------------- K3: wave-per-row-octet gather + fused final (atomicAdd out) ----------------
__global__ __launch_bounds__(256) void k_reduce(
    const float* __restrict__ part_row, const float* __restrict__ part_col,
    const float* __restrict__ pos_partial, const float* __restrict__ augacc,
    float* __restrict__ out) {
  const int w = threadIdx.x >> 6, lane = threadIdx.x & 63;
  float s = 0.0f;
#pragma unroll
  for (int i = 0; i < 8; ++i) {
    const int r = blockIdx.x * 32 + w * 8 + i;
    const int I = r >> 7, rr = r & 127;
    const size_t base = (size_t)(I * 64 + lane) * 128 + rr;
    float v = 0.0f;
    if (lane >= I) v += part_row[base];
    if (lane <= I) v += part_col[base];
#pragma unroll
    for (int m = 1; m < 64; m <<= 1) v += __shfl_xor(v, m, 64);
    if (lane == 0) {
      float tl = 8.0f * logf(v + LOSS_EPS);
      tl -= pos_partial[r];
      tl -= pos_partial[r + TWO_B];
      tl -= pos_partial[r + 2 * TWO_B];
      tl -= pos_partial[r + 3 * TWO_B];
      s += tl;
    }
  }
  __shared__ float red[4];
  if (lane == 0) red[w] = s;
  __syncthreads();
  if (threadIdx.x == 0) {
    float bs = red[0] + red[1] + red[2] + red[3];
    if (blockIdx.x == 0) bs -= 8.0f * LN2 * augacc[0];  // aug positives from gram
    atomicAdd(out, bs * (1.0f / 65536.0f));
  }
}

extern "C" void kernel_launch(void* const* d_in, const int* in_sizes, int n_in,
                              void* d_out, int out_size, void* d_ws, size_t ws_size,
                              hipStream_t stream) {
  const float* z1 = (const float*)d_in[0];
  const float* z2 = (const float*)d_in[1];
  const float* zn = (const float*)d_in[2];
  float* out = (float*)d_out;

  char* ws = (char*)d_ws;
  __hip_bfloat16* za_n = (__hip_bfloat16*)ws;                  // 2 MB
  float* inv_zn      = (float*)(ws + 2097152);                 // 64 KB
  float* pos_partial = (float*)(ws + 2097152 + 65536);         // 128 KB
  float* augacc      = (float*)(ws + 2097152 + 65536 + 131072);          // 4 KB slot
  float* part_row    = (float*)(ws + 2097152 + 65536 + 131072 + 4096);   // 2 MB
  float* part_col    = (float*)(ws + 2097152 + 65536 + 131072 + 4096 + 2097152); // 2 MB

  // K1: normalize (1 wave / 2 rows) + zero augacc/out
  k_normalize<<<(TWO_B + NB) / 8, 256, 0, stream>>>(z1, z2, zn, za_n, inv_zn, augacc, out);
  // K2: symmetric gram partials + fused nearby positives (XCD swizzle + A prefetch)
  k_gram<<<GRAM_BLOCKS, 256, 0, stream>>>(za_n, zn, inv_zn, part_row, part_col,
                                          pos_partial, augacc);
  // K3: gather/log/subtract + fused final scalar
  k_reduce<<<256, 256, 0, stream>>>(part_row, part_col, pos_partial, augacc, out);
}